// Round 4
// baseline (384.955 us; speedup 1.0000x reference)
//
#include <hip/hip_runtime.h>
#include <stdint.h>

#define C_DIM 8192
#define O_DIM 8192
#define M_DIM 256
#define NG    128     // C/64 groups
#define RK    32

typedef float f32x4 __attribute__((ext_vector_type(4)));
typedef int   i32x4 __attribute__((ext_vector_type(4)));
typedef unsigned int u32;

// ---------------------------------------------------------------------------
// k_lora: lact[m][r] = sum_k x[m][k] * pd[k][r]   (256 x 32, f32)
// grid 128 blocks * 256 threads; thread = (ml, kc, rq) with rq FASTEST so
// pd loads are 128B-contiguous per 8 lanes (was 16B scatter before).
// ---------------------------------------------------------------------------
__global__ __launch_bounds__(256) void k_lora(const float* __restrict__ x,
                                              const float* __restrict__ pd,
                                              float* __restrict__ lact) {
  const int t  = threadIdx.x;
  const int rq = t & 7;           // r-quad (fastest -> coalesced pd)
  const int kc = (t >> 3) & 15;   // k-chunk of 512
  const int ml = t >> 7;          // 0..1
  const int m  = blockIdx.x * 2 + ml;
  const float* xrow = x + (size_t)m * C_DIM + kc * 512;
  const float* pdp  = pd + (size_t)(kc * 512) * RK + rq * 4;
  float a0 = 0.f, a1 = 0.f, a2 = 0.f, a3 = 0.f;
  for (int k = 0; k < 512; k += 4) {
    float4 xv = *(const float4*)(xrow + k);
    float4 p0 = *(const float4*)(pdp + (size_t)(k + 0) * RK);
    float4 p1 = *(const float4*)(pdp + (size_t)(k + 1) * RK);
    float4 p2 = *(const float4*)(pdp + (size_t)(k + 2) * RK);
    float4 p3 = *(const float4*)(pdp + (size_t)(k + 3) * RK);
    a0 += xv.x * p0.x + xv.y * p1.x + xv.z * p2.x + xv.w * p3.x;
    a1 += xv.x * p0.y + xv.y * p1.y + xv.z * p2.y + xv.w * p3.y;
    a2 += xv.x * p0.z + xv.y * p1.z + xv.z * p2.z + xv.w * p3.z;
    a3 += xv.x * p0.w + xv.y * p1.w + xv.z * p2.w + xv.w * p3.w;
  }
  __shared__ float red[2][8][16][4];
  red[ml][rq][kc][0] = a0;
  red[ml][rq][kc][1] = a1;
  red[ml][rq][kc][2] = a2;
  red[ml][rq][kc][3] = a3;
  __syncthreads();
  if (t < 64) {
    const int ml2 = t >> 5, r = t & 31, rq2 = r >> 2, j = r & 3;
    float s = 0.f;
#pragma unroll
    for (int c = 0; c < 16; ++c) s += red[ml2][rq2][c][j];
    lact[(size_t)(blockIdx.x * 2 + ml2) * RK + r] = s;
  }
}

// ---------------------------------------------------------------------------
// k_prep: smooth + per-group int4 quantize of activations.
// Outputs:
//   asc[g][m]  = ascale (f32)
//   rsa[g][m]  = 8 * (sum_k q) * ascale   (rowsum correction, f32)
//   wsA8: i8 A-fragments for mfma_i32_16x16x64_i8:
//     frag (MT,g): lane l holds bytes j=0..15 = q[m=MT*16+(l&15)][k=(l>>4)*16+j]
//     stored as i32x4 at index ((MT*NG+g)*64 + l)
// grid = 16 MT * 8 gblk = 128 blocks * 256 threads; thread=(gl,ml)
// ---------------------------------------------------------------------------
__global__ __launch_bounds__(256) void k_prep(const float* __restrict__ x,
                                              const float* __restrict__ smooth,
                                              float* __restrict__ asc,
                                              float* __restrict__ rsa,
                                              i32x4* __restrict__ wsA8) {
  const int t    = threadIdx.x;
  const int ml   = t & 15;
  const int gl   = t >> 4;
  const int MT   = blockIdx.x >> 3;
  const int gblk = blockIdx.x & 7;
  const int m = MT * 16 + ml;
  const int g = gblk * 16 + gl;
  const float* xp = x + (size_t)m * C_DIM + g * 64;
  const float* sp = smooth + g * 64;
  float xs[64];
  float amax = 0.0f;
#pragma unroll
  for (int i = 0; i < 64; i += 4) {
    float4 xv = *(const float4*)(xp + i);
    float4 sv = *(const float4*)(sp + i);
    xs[i + 0] = xv.x / sv.x;
    xs[i + 1] = xv.y / sv.y;
    xs[i + 2] = xv.z / sv.z;
    xs[i + 3] = xv.w / sv.w;
    amax = fmaxf(amax, fabsf(xs[i + 0]));
    amax = fmaxf(amax, fabsf(xs[i + 1]));
    amax = fmaxf(amax, fabsf(xs[i + 2]));
    amax = fmaxf(amax, fabsf(xs[i + 3]));
  }
  const float ascale = fmaxf(amax / 7.0f, 1e-8f);   // match reference exactly
  int qi[64];
  int rs = 0;
#pragma unroll
  for (int i = 0; i < 64; ++i) {
    float qv = fminf(fmaxf(rintf(xs[i] / ascale), -8.0f), 7.0f);
    qi[i] = (int)qv;
    rs += qi[i];
  }
  asc[(size_t)g * M_DIM + m] = ascale;
  rsa[(size_t)g * M_DIM + m] = 8.0f * (float)rs * ascale;
  const size_t base = ((size_t)(MT * NG + g)) * 64;
#pragma unroll
  for (int lg = 0; lg < 4; ++lg) {
    const int* q = qi + lg * 16;
    i32x4 c;
#pragma unroll
    for (int dw = 0; dw < 4; ++dw)
      c[dw] = (q[dw * 4 + 0] & 0xff) | ((q[dw * 4 + 1] & 0xff) << 8) |
              ((q[dw * 4 + 2] & 0xff) << 16) | (q[dw * 4 + 3] << 24);
    wsA8[base + lg * 16 + ml] = c;
  }
}

// ---------------------------------------------------------------------------
// k_main: out[m][n] = sum_g ws[g][n]*(as[g][m]*idot - rsa[g][m])
//                   + bias[n] + lact[m].pu[n]
// where idot = sum_k qa * code (code = raw qweight 0..15; exact i8 MFMA).
// grid 512 blocks (16 n-cols each) * 512 threads = 8 independent waves.
// Wave w: m-tiles {2w, 2w+1} (32 rows). NO LDS, NO barriers: each wave
// loads its B fragment straight from qweight (lines shared via L1/L2),
// depth-2 B prefetch, depth-1 A/scale prefetch.
// ---------------------------------------------------------------------------
__global__ __launch_bounds__(512, 4) void k_main(
    const int* __restrict__ qw, const float* __restrict__ wsc,
    const float* __restrict__ pu, const float* __restrict__ bias,
    const float* __restrict__ asc, const float* __restrict__ rsa,
    const i32x4* __restrict__ wsA8, const float* __restrict__ lact,
    float* __restrict__ out) {
  const int t    = threadIdx.x;
  const int n0   = blockIdx.x * 16;
  const int w    = t >> 6;
  const int l    = t & 63;
  const int lrow = l >> 4;    // 0..3  (k-slice for B, row-quad for C)
  const int lcol = l & 15;    // col within n-tile / row within A
  const int MT0  = w * 2;

  // B: lane covers col=lcol, k=[lrow*16, lrow*16+16) of each group
  const i32x4* qbase =
      (const i32x4*)(qw + (size_t)(n0 + lcol) * C_DIM + lrow * 16);

  f32x4 acc[2];
  acc[0] = (f32x4){0.f, 0.f, 0.f, 0.f};
  acc[1] = (f32x4){0.f, 0.f, 0.f, 0.f};

  i32x4 braw[2][4];
  i32x4 aC[2], aN[2];
  f32x4 asC[2], asN[2], rsC[2], rsN[2];
  float wsCv, wsNv;

  auto LDB = [&](int g, i32x4 (&br)[4]) {
    const i32x4* p = qbase + (size_t)g * 16;
#pragma unroll
    for (int i = 0; i < 4; ++i) br[i] = p[i];
  };
  auto LDA = [&](int g, i32x4 (&a)[2]) {
#pragma unroll
    for (int mt = 0; mt < 2; ++mt)
      a[mt] = wsA8[((size_t)(MT0 + mt) * NG + g) * 64 + l];
  };
  auto LDSC = [&](int g, f32x4 (&as)[2], f32x4 (&rr)[2], float& wsv) {
#pragma unroll
    for (int mt = 0; mt < 2; ++mt) {
      const size_t o = (size_t)g * M_DIM + (MT0 + mt) * 16 + lrow * 4;
      as[mt] = *(const f32x4*)(asc + o);
      rr[mt] = *(const f32x4*)(rsa + o);
    }
    wsv = wsc[(size_t)g * O_DIM + n0 + lcol];
  };

  // prologue
  LDB(0, braw[0]);
  LDB(1, braw[1]);
  LDA(0, aC);
  LDSC(0, asC, rsC, wsCv);

  for (int g = 0; g < NG; ++g) {
    if (g < NG - 1) {
      LDA(g + 1, aN);
      LDSC(g + 1, asN, rsN, wsNv);
    }
    // pack raw codes (0..15) -> i8 bytes, k ascending within lane
    i32x4* br = braw[g & 1];
    i32x4 bf;
#pragma unroll
    for (int i = 0; i < 4; ++i)
      bf[i] = (br[i][0] & 0xff) | ((br[i][1] & 0xff) << 8) |
              ((br[i][2] & 0xff) << 16) | (br[i][3] << 24);
    if (g < NG - 2) LDB(g + 2, braw[g & 1]);

    const i32x4 z = (i32x4){0, 0, 0, 0};
#pragma unroll
    for (int mt = 0; mt < 2; ++mt) {
      i32x4 d = __builtin_amdgcn_mfma_i32_16x16x64_i8(aC[mt], bf, z, 0, 0, 0);
      f32x4 df;
      df[0] = (float)d[0];
      df[1] = (float)d[1];
      df[2] = (float)d[2];
      df[3] = (float)d[3];
      f32x4 tt = asC[mt] * df - rsC[mt];
      acc[mt] += wsCv * tt;
    }

    if (g < NG - 1) {
#pragma unroll
      for (int mt = 0; mt < 2; ++mt) {
        aC[mt] = aN[mt];
        asC[mt] = asN[mt];
        rsC[mt] = rsN[mt];
      }
      wsCv = wsNv;
    }
  }

  // epilogue: + bias + lora
  const int n = n0 + lcol;
  const float bv = bias[n];
  float4 puq[8];
#pragma unroll
  for (int rq = 0; rq < 8; ++rq)
    puq[rq] = *(const float4*)(pu + (size_t)n * RK + rq * 4);
#pragma unroll
  for (int mt = 0; mt < 2; ++mt) {
#pragma unroll
    for (int j = 0; j < 4; ++j) {
      const int m = (MT0 + mt) * 16 + lrow * 4 + j;
      const float* lp = lact + (size_t)m * RK;
      float lo = 0.f;
#pragma unroll
      for (int rq = 0; rq < 8; ++rq) {
        float4 lv = *(const float4*)(lp + rq * 4);
        lo += lv.x * puq[rq].x + lv.y * puq[rq].y + lv.z * puq[rq].z +
              lv.w * puq[rq].w;
      }
      out[(size_t)m * O_DIM + n] = acc[mt][j] + bv + lo;
    }
  }
}

// ---------------------------------------------------------------------------
extern "C" void kernel_launch(void* const* d_in, const int* in_sizes, int n_in,
                              void* d_out, int out_size, void* d_ws,
                              size_t ws_size, hipStream_t stream) {
  const float* x      = (const float*)d_in[0];
  const int*   qw     = (const int*)d_in[1];
  const float* wsc    = (const float*)d_in[2];
  const float* smooth = (const float*)d_in[3];
  const float* pd     = (const float*)d_in[4];
  const float* pu     = (const float*)d_in[5];
  const float* bias   = (const float*)d_in[6];
  float* out = (float*)d_out;

  char* ws = (char*)d_ws;
  float* lact = (float*)ws;                     // 256*32*4   = 32 KB
  float* asc  = (float*)(ws + 32 * 1024);       // 128*256*4  = 128 KB
  float* rsa  = (float*)(ws + 160 * 1024);      // 128*256*4  = 128 KB
  i32x4* wsA8 = (i32x4*)(ws + 288 * 1024);      // 2 MB i8 A-fragments

  hipLaunchKernelGGL(k_prep, dim3(128), dim3(256), 0, stream, x, smooth, asc,
                     rsa, wsA8);
  hipLaunchKernelGGL(k_lora, dim3(128), dim3(256), 0, stream, x, pd, lact);
  hipLaunchKernelGGL(k_main, dim3(512), dim3(512), 0, stream, qw, wsc, pu, bias,
                     asc, rsa, wsA8, lact, out);
}

// Round 6
// 181.605 us; speedup vs baseline: 2.1197x; 2.1197x over previous
//
#include <hip/hip_runtime.h>
#include <stdint.h>

#define C_DIM 8192
#define O_DIM 8192
#define M_DIM 256
#define NG    128     // C/64 groups
#define RK    32

typedef float f32x4 __attribute__((ext_vector_type(4)));
typedef int   i32x4 __attribute__((ext_vector_type(4)));
typedef unsigned int u32;

__device__ __forceinline__ void gll16(const void* g, void* l) {
  __builtin_amdgcn_global_load_lds(
      (const __attribute__((address_space(1))) void*)g,
      (__attribute__((address_space(3))) void*)l, 16, 0, 0);
}

// ---------------------------------------------------------------------------
// k_lora: lact[m][r] = sum_k x[m][k] * pd[k][r]   (256 x 32, f32)
// ---------------------------------------------------------------------------
__global__ __launch_bounds__(256) void k_lora(const float* __restrict__ x,
                                              const float* __restrict__ pd,
                                              float* __restrict__ lact) {
  const int t  = threadIdx.x;
  const int rq = t & 7;           // r-quad fastest -> coalesced pd
  const int kc = (t >> 3) & 15;
  const int ml = t >> 7;
  const int m  = blockIdx.x * 2 + ml;
  const float* xrow = x + (size_t)m * C_DIM + kc * 512;
  const float* pdp  = pd + (size_t)(kc * 512) * RK + rq * 4;
  float a0 = 0.f, a1 = 0.f, a2 = 0.f, a3 = 0.f;
  for (int k = 0; k < 512; k += 4) {
    float4 xv = *(const float4*)(xrow + k);
    float4 p0 = *(const float4*)(pdp + (size_t)(k + 0) * RK);
    float4 p1 = *(const float4*)(pdp + (size_t)(k + 1) * RK);
    float4 p2 = *(const float4*)(pdp + (size_t)(k + 2) * RK);
    float4 p3 = *(const float4*)(pdp + (size_t)(k + 3) * RK);
    a0 += xv.x * p0.x + xv.y * p1.x + xv.z * p2.x + xv.w * p3.x;
    a1 += xv.x * p0.y + xv.y * p1.y + xv.z * p2.y + xv.w * p3.y;
    a2 += xv.x * p0.z + xv.y * p1.z + xv.z * p2.z + xv.w * p3.z;
    a3 += xv.x * p0.w + xv.y * p1.w + xv.z * p2.w + xv.w * p3.w;
  }
  __shared__ float red[2][8][16][4];
  red[ml][rq][kc][0] = a0;
  red[ml][rq][kc][1] = a1;
  red[ml][rq][kc][2] = a2;
  red[ml][rq][kc][3] = a3;
  __syncthreads();
  if (t < 64) {
    const int ml2 = t >> 5, r = t & 31, rq2 = r >> 2, j = r & 3;
    float s = 0.f;
#pragma unroll
    for (int c = 0; c < 16; ++c) s += red[ml2][rq2][c][j];
    lact[(size_t)(blockIdx.x * 2 + ml2) * RK + r] = s;
  }
}

// ---------------------------------------------------------------------------
// k_prep: smooth + per-group int4 quantize.
//   scp[g*512 + m]       = ascale
//   scp[g*512 + 256 + m] = 8 * (sum_k q) * ascale
//   wsA8[(MT*NG+g)*64+l] = 16 i8: q[m=MT*16+(l&15)][k=(l>>4)*16+j]
// ---------------------------------------------------------------------------
__global__ __launch_bounds__(256) void k_prep(const float* __restrict__ x,
                                              const float* __restrict__ smooth,
                                              float* __restrict__ scp,
                                              i32x4* __restrict__ wsA8) {
  const int t    = threadIdx.x;
  const int ml   = t & 15;
  const int gl   = t >> 4;
  const int MT   = blockIdx.x >> 3;
  const int gblk = blockIdx.x & 7;
  const int m = MT * 16 + ml;
  const int g = gblk * 16 + gl;
  const float* xp = x + (size_t)m * C_DIM + g * 64;
  const float* sp = smooth + g * 64;
  float xs[64];
  float amax = 0.0f;
#pragma unroll
  for (int i = 0; i < 64; i += 4) {
    float4 xv = *(const float4*)(xp + i);
    float4 sv = *(const float4*)(sp + i);
    xs[i + 0] = xv.x / sv.x;
    xs[i + 1] = xv.y / sv.y;
    xs[i + 2] = xv.z / sv.z;
    xs[i + 3] = xv.w / sv.w;
    amax = fmaxf(amax, fabsf(xs[i + 0]));
    amax = fmaxf(amax, fabsf(xs[i + 1]));
    amax = fmaxf(amax, fabsf(xs[i + 2]));
    amax = fmaxf(amax, fabsf(xs[i + 3]));
  }
  const float ascale = fmaxf(amax / 7.0f, 1e-8f);
  int qi[64];
  int rs = 0;
#pragma unroll
  for (int i = 0; i < 64; ++i) {
    float qv = fminf(fmaxf(rintf(xs[i] / ascale), -8.0f), 7.0f);
    qi[i] = (int)qv;
    rs += qi[i];
  }
  scp[(size_t)g * 512 + m]       = ascale;
  scp[(size_t)g * 512 + 256 + m] = 8.0f * (float)rs * ascale;
  const size_t base = ((size_t)(MT * NG + g)) * 64;
#pragma unroll
  for (int lg = 0; lg < 4; ++lg) {
    const int* q = qi + lg * 16;
    i32x4 c;
#pragma unroll
    for (int dw = 0; dw < 4; ++dw)
      c[dw] = (q[dw * 4 + 0] & 0xff) | ((q[dw * 4 + 1] & 0xff) << 8) |
              ((q[dw * 4 + 2] & 0xff) << 16) | (q[dw * 4 + 3] << 24);
    wsA8[base + lg * 16 + ml] = c;
  }
}

// ---------------------------------------------------------------------------
// k_main: 512 blocks x 256 thr (4 waves), 2 blocks/CU. Block = 16 n x 256 m.
// Wave w owns m-tiles {4w..4w+3}. qweight staged via global_load_lds into a
// 4-deep LDS ring (counted vmcnt, raw s_barrier, never drained). Scales
// staged per pair; wscale column preloaded once. Loop unrolled x2 (static
// A double-buffer indices). XOR-swizzled LDS reads (chunk ^= row&7).
// ---------------------------------------------------------------------------
__global__ __launch_bounds__(256, 2) void k_main(
    const int* __restrict__ qw, const float* __restrict__ wsc,
    const float* __restrict__ pu, const float* __restrict__ bias,
    const float* __restrict__ scp, const i32x4* __restrict__ wsA8,
    const float* __restrict__ lact, float* __restrict__ out) {
  const int t    = threadIdx.x;
  const int n0   = blockIdx.x * 16;
  const int w    = t >> 6;
  const int l    = t & 63;
  const int lrow = l >> 4;
  const int lcol = l & 15;
  const int MTb  = w * 4;

  __shared__ int   ldsB[4][1024];    // 4 x 4KB raw-code ring
  __shared__ float ldsSC[2][1024];   // 2 x 4KB scale pair ring {as256,rs256}x2
  __shared__ float ldsW[NG * 16];    // 8KB wscale table

  // one-time wscale table
  for (int i = t; i < NG * 16; i += 256) {
    int g = i >> 4, c = i & 15;
    ldsW[i] = wsc[(size_t)g * O_DIM + n0 + c];
  }

  // staging addresses: thread t -> slot (row sr, chunk-slot sc'); source
  // chunk = sc' ^ (sr&7) so LDS stays linear (swizzle on the source).
  const int sr     = t >> 4;
  const int scp_   = t & 15;
  const int schunk = scp_ ^ (sr & 7);
  const int*   gB  = qw + (size_t)(n0 + sr) * C_DIM + schunk * 4;
  const float* gSC = scp + t * 4;

  __syncthreads();

  // prologue issue order: bS(0), scS(0), A(0)x4, bS(1)
  gll16(gB, &ldsB[0][t * 4]);
  gll16(gSC, &ldsSC[0][t * 4]);
  i32x4 A0[4], A1[4];
#pragma unroll
  for (int mi = 0; mi < 4; ++mi)
    A0[mi] = wsA8[((size_t)(MTb + mi) * NG + 0) * 64 + l];
  gll16(gB + 64, &ldsB[1][t * 4]);

  f32x4 acc[4];
#pragma unroll
  for (int mi = 0; mi < 4; ++mi) acc[mi] = (f32x4){0.f, 0.f, 0.f, 0.f};

  const i32x4 z = (i32x4){0, 0, 0, 0};
  const int rsw = (lcol & 7);   // read-side swizzle for this lane's row

#define BODY(G, AC, AN, VMC, DO_SC)                                            \
  {                                                                            \
    asm volatile("s_waitcnt vmcnt(" #VMC ")" ::: "memory");                    \
    __builtin_amdgcn_s_barrier();                                              \
    const int bb = (G) & 3;                                                    \
    i32x4 raw0 = *(const i32x4*)&ldsB[bb][lcol * 64 + ((lrow * 4 + 0) ^ rsw) * 4]; \
    i32x4 raw1 = *(const i32x4*)&ldsB[bb][lcol * 64 + ((lrow * 4 + 1) ^ rsw) * 4]; \
    i32x4 raw2 = *(const i32x4*)&ldsB[bb][lcol * 64 + ((lrow * 4 + 2) ^ rsw) * 4]; \
    i32x4 raw3 = *(const i32x4*)&ldsB[bb][lcol * 64 + ((lrow * 4 + 3) ^ rsw) * 4]; \
    i32x4 bf;                                                                  \
    bf[0] = raw0[0] | (raw0[1] << 8) | (raw0[2] << 16) | (raw0[3] << 24);      \
    bf[1] = raw1[0] | (raw1[1] << 8) | (raw1[2] << 16) | (raw1[3] << 24);      \
    bf[2] = raw2[0] | (raw2[1] << 8) | (raw2[2] << 16) | (raw2[3] << 24);      \
    bf[3] = raw3[0] | (raw3[1] << 8) | (raw3[2] << 16) | (raw3[3] << 24);      \
    /* next-iter loads: A(G+1) first, then glls (vmcnt counting) */            \
    {                                                                          \
      int gn = (G) + 1; if (gn > NG - 1) gn = NG - 1;                          \
      _Pragma("unroll")                                                        \
      for (int mi = 0; mi < 4; ++mi)                                           \
        AN[mi] = wsA8[((size_t)(MTb + mi) * NG + gn) * 64 + l];                \
    }                                                                          \
    if (DO_SC) {                                                               \
      int pn = ((G) >> 1) + 1; if (pn > 63) pn = 63;                           \
      gll16(gSC + (size_t)pn * 1024, &ldsSC[pn & 1][t * 4]);                   \
    }                                                                          \
    {                                                                          \
      int gs = (G) + 2; if (gs > NG - 1) gs = NG - 1;                          \
      gll16(gB + (size_t)gs * 64, &ldsB[gs & 3][t * 4]);                       \
    }                                                                          \
    const int sb = ((G) >> 1) & 1;                                             \
    const int gh = ((G) & 1) * 512;                                            \
    const float wsv = ldsW[(G) * 16 + lcol];                                   \
    _Pragma("unroll")                                                          \
    for (int mi = 0; mi < 4; ++mi) {                                           \
      f32x4 asv = *(const f32x4*)&ldsSC[sb][gh + (MTb + mi) * 16 + lrow * 4];  \
      f32x4 rsv = *(const f32x4*)&ldsSC[sb][gh + 256 + (MTb + mi) * 16 + lrow * 4]; \
      i32x4 d = __builtin_amdgcn_mfma_i32_16x16x64_i8(AC[mi], bf, z, 0, 0, 0); \
      f32x4 df;                                                                \
      df[0] = (float)d[0]; df[1] = (float)d[1];                                \
      df[2] = (float)d[2]; df[3] = (float)d[3];                                \
      acc[mi] += wsv * (asv * df - rsv);                                       \
    }                                                                          \
  }

  for (int p = 0; p < NG / 2; ++p) {
    const int g0 = p * 2;
    BODY(g0, A0, A1, 1, 1);       // even: wait vmcnt(1), stage next sc pair
    BODY(g0 + 1, A1, A0, 2, 0);   // odd:  wait vmcnt(2)
  }
#undef BODY

  // epilogue: + bias + lora
  const int n = n0 + lcol;
  const float bv = bias[n];
  float4 puq[8];
#pragma unroll
  for (int rq = 0; rq < 8; ++rq)
    puq[rq] = *(const float4*)(pu + (size_t)n * RK + rq * 4);
#pragma unroll
  for (int mi = 0; mi < 4; ++mi) {
#pragma unroll
    for (int j = 0; j < 4; ++j) {
      const int m = (MTb + mi) * 16 + lrow * 4 + j;
      const float* lp = lact + (size_t)m * RK;
      float lo = 0.f;
#pragma unroll
      for (int rq = 0; rq < 8; ++rq) {
        float4 lv = *(const float4*)(lp + rq * 4);
        lo += lv.x * puq[rq].x + lv.y * puq[rq].y + lv.z * puq[rq].z +
              lv.w * puq[rq].w;
      }
      out[(size_t)m * O_DIM + n] = acc[mi][j] + bv + lo;
    }
  }
}

// ---------------------------------------------------------------------------
extern "C" void kernel_launch(void* const* d_in, const int* in_sizes, int n_in,
                              void* d_out, int out_size, void* d_ws,
                              size_t ws_size, hipStream_t stream) {
  const float* x      = (const float*)d_in[0];
  const int*   qw     = (const int*)d_in[1];
  const float* wsc    = (const float*)d_in[2];
  const float* smooth = (const float*)d_in[3];
  const float* pd     = (const float*)d_in[4];
  const float* pu     = (const float*)d_in[5];
  const float* bias   = (const float*)d_in[6];
  float* out = (float*)d_out;

  char* ws = (char*)d_ws;
  float* lact = (float*)ws;                     // 32 KB
  float* scp  = (float*)(ws + 32 * 1024);       // 128*512*4 = 256 KB
  i32x4* wsA8 = (i32x4*)(ws + 288 * 1024);      // 2 MB i8 A-fragments

  hipLaunchKernelGGL(k_prep, dim3(128), dim3(256), 0, stream, x, smooth, scp,
                     wsA8);
  hipLaunchKernelGGL(k_lora, dim3(128), dim3(256), 0, stream, x, pd, lact);
  hipLaunchKernelGGL(k_main, dim3(512), dim3(256), 0, stream, qw, wsc, pu, bias,
                     scp, wsA8, lact, out);
}